// Round 2
// baseline (293.531 us; speedup 1.0000x reference)
//
#include <hip/hip_runtime.h>
#include <hip/hip_bf16.h>
#include <stdint.h>

#define D_DIM 512
#define B_CTX 512
#define M_MEM 65536
#define BM 128
#define BB 128
#define BK 32
#define GBK 64               // K-step of the fast bf16 GEMM (m97 structure)
#define LDSPAD 40            // 80 B row pitch for legacy fallback kernel
#define DELTA_COS 2.5e-3f    // ~35 sigma of bf16 cosine noise, scale-invariant
#define LISTCAP 2048
#define CVT_MEM_BLOCKS (M_MEM / 32)            // 2048: 4 waves x 8 rows each
#define CVT_BLOCKS (CVT_MEM_BLOCKS + B_CTX / 32)

typedef __attribute__((ext_vector_type(8))) short short8;   // 8 bf16 (4 VGPR)
typedef __attribute__((ext_vector_type(4))) float floatx4;  // MFMA accumulator

__device__ __forceinline__ uint32_t f32_order(float s) {    // monotone f32->u32
    uint32_t u = __float_as_uint(s);
    return (u & 0x80000000u) ? ~u : (u | 0x80000000u);
}
__device__ __forceinline__ float f32_unorder(uint32_t v) {
    uint32_t u = (v & 0x80000000u) ? (v & 0x7FFFFFFFu) : ~v;
    return __uint_as_float(u);
}
__device__ __forceinline__ uint32_t pack_bf16_rtn(float a, float b) {
    uint32_t ua = __float_as_uint(a) + 0x8000u;
    uint32_t ub = __float_as_uint(b) + 0x8000u;
    return (ua >> 16) | (ub & 0xFFFF0000u);
}

// async global->LDS, 16B per lane. LDS dest is WAVE-UNIFORM base; HW adds lane*16.
typedef const __attribute__((address_space(1))) void gv_t;
typedef __attribute__((address_space(3))) void lv_t;
__device__ __forceinline__ void gload_lds16(const uint16_t* g, uint16_t* l) {
    __builtin_amdgcn_global_load_lds((gv_t*)g, (lv_t*)l, 16, 0, 0);
}

// ---------------- kernel 0: dtype probe ----------------
__global__ void detect_init(const uint32_t* __restrict__ mem_raw,
                            uint32_t* __restrict__ flag) {
    __shared__ int cnt;
    if (threadIdx.x == 0) cnt = 0;
    __syncthreads();
    int s = 0;
    #pragma unroll
    for (int i = 0; i < 8; ++i) {
        uint32_t u = mem_raw[threadIdx.x * 8 + i];
        uint32_t e = (u >> 7) & 0xFFu;   // exponent of LOW bf16 half
        s += (e >= 96u && e <= 144u) ? 1 : 0;
    }
    atomicAdd(&cnt, s);
    __syncthreads();
    if (threadIdx.x == 0) *flag = (cnt > 256) ? 1u : 0u;   // 1 == bf16 inputs
}

// ---- kernel A: one-pass convert. mem -> bf16(mem * 1/|mem|), ctx -> bf16(ctx) ----
// One wave per 8 rows; lane holds 8 contiguous elements (32B fp32 in, 16B bf16 out).
__global__ __launch_bounds__(256) void convert_scale(const void* __restrict__ ctxv,
                                                     const void* __restrict__ memv,
                                                     const uint32_t* __restrict__ flag,
                                                     uint16_t* __restrict__ mem_s,
                                                     uint16_t* __restrict__ ctx_b) {
    const bool isbf = (*flag != 0u);
    const int lane = threadIdx.x & 63;
    const int w = threadIdx.x >> 6;
    if (blockIdx.x < CVT_MEM_BLOCKS) {
        const int gw = blockIdx.x * 4 + w;           // 0..8191
        #pragma unroll
        for (int i = 0; i < 8; ++i) {
            const int r = gw * 8 + i;                // 0..65535
            float x[8];
            if (isbf) {
                uint4 v = *((const uint4*)((const uint16_t*)memv + (size_t)r * D_DIM) + lane);
                uint32_t ww[4] = {v.x, v.y, v.z, v.w};
                #pragma unroll
                for (int j = 0; j < 4; ++j) {
                    x[2 * j]     = __uint_as_float(ww[j] << 16);
                    x[2 * j + 1] = __uint_as_float(ww[j] & 0xFFFF0000u);
                }
            } else {
                const float4* p = (const float4*)((const float*)memv + (size_t)r * D_DIM) + lane * 2;
                float4 a = p[0], bq = p[1];
                x[0] = a.x; x[1] = a.y; x[2] = a.z; x[3] = a.w;
                x[4] = bq.x; x[5] = bq.y; x[6] = bq.z; x[7] = bq.w;
            }
            float nsq = 0.f;
            #pragma unroll
            for (int j = 0; j < 8; ++j) nsq = fmaf(x[j], x[j], nsq);
            #pragma unroll
            for (int o = 32; o; o >>= 1) nsq += __shfl_xor(nsq, o, 64);
            const float invn = rsqrtf(fmaxf(nsq, 1e-12f));
            uint4 ov;
            ov.x = pack_bf16_rtn(x[0] * invn, x[1] * invn);
            ov.y = pack_bf16_rtn(x[2] * invn, x[3] * invn);
            ov.z = pack_bf16_rtn(x[4] * invn, x[5] * invn);
            ov.w = pack_bf16_rtn(x[6] * invn, x[7] * invn);
            *((uint4*)(mem_s + (size_t)r * D_DIM) + lane) = ov;
        }
    } else {
        const int gw = (blockIdx.x - CVT_MEM_BLOCKS) * 4 + w;   // 0..63
        #pragma unroll
        for (int i = 0; i < 8; ++i) {
            const int r = gw * 8 + i;                // 0..511
            uint4 ov;
            if (isbf) {
                ov = *((const uint4*)((const uint16_t*)ctxv + (size_t)r * D_DIM) + lane);
            } else {
                const float4* p = (const float4*)((const float*)ctxv + (size_t)r * D_DIM) + lane * 2;
                float4 a = p[0], bq = p[1];
                ov.x = pack_bf16_rtn(a.x, a.y);
                ov.y = pack_bf16_rtn(a.z, a.w);
                ov.z = pack_bf16_rtn(bq.x, bq.y);
                ov.w = pack_bf16_rtn(bq.z, bq.w);
            }
            *((uint4*)(ctx_b + (size_t)r * D_DIM) + lane) = ov;
        }
    }
}

// ---- kernel B: pure-bf16 MFMA GEMM (m97 structure: linear LDS + global_load_lds,
// BK=64) + per-(b, 16-row-group) max. Keys are pre-normalized: key = acc directly. ----
__global__ __launch_bounds__(256) void score_mfma(const uint16_t* __restrict__ A,   // mem_s [M][512]
                                                  const uint16_t* __restrict__ Bc,  // ctx_b [B][512]
                                                  uint32_t* __restrict__ tmax,
                                                  int coarse) {
    __shared__ __align__(16) uint16_t at[BM][GBK];   // 16 KB, LINEAR (global_load_lds dest)
    __shared__ __align__(16) uint16_t bt[BB][GBK];   // 16 KB
    __shared__ uint32_t s_gbest[8][BB];

    const int t    = threadIdx.x;
    const int b0   = blockIdx.x * BB;
    const int m0   = blockIdx.y * BM;
    const int lane = t & 63;
    const int w    = t >> 6;
    const int wm   = w >> 1;
    const int wb   = w & 1;
    const int quad = lane >> 4;
    const int l15  = lane & 15;
    const int srow = t >> 3;          // 0..31 (+32 per issue)
    const int scol = (t & 7) * 8;     // element col of this thread's 16B chunk

    floatx4 acc[4][4];
    #pragma unroll
    for (int i = 0; i < 4; ++i)
        #pragma unroll
        for (int j = 0; j < 4; ++j)
            acc[i][j] = (floatx4){0.f, 0.f, 0.f, 0.f};

    for (int k0 = 0; k0 < D_DIM; k0 += GBK) {
        __syncthreads();               // previous tile's ds_reads done
        #pragma unroll
        for (int q = 0; q < 4; ++q) {
            const int r = srow + q * 32;
            // wave-uniform LDS base (chunks q*256 + w*64); HW scatters lane i at +i*16B.
            // lane i of wave w stages global row (m0 + q*32 + w*8 + i/8), col (i&7)*8
            // which is exactly LDS chunk (q*256 + w*64 + i) in the linear [128][64] tile.
            gload_lds16(A  + (size_t)(m0 + r) * D_DIM + k0 + scol,
                        &at[0][0] + (size_t)(q * 256 + (w << 6)) * 8);
            gload_lds16(Bc + (size_t)(b0 + r) * D_DIM + k0 + scol,
                        &bt[0][0] + (size_t)(q * 256 + (w << 6)) * 8);
        }
        __syncthreads();               // compiler drains vmcnt(0) here
        #pragma unroll
        for (int kk = 0; kk < 2; ++kk) {
            short8 af[4], bg[4];
            #pragma unroll
            for (int i = 0; i < 4; ++i)
                af[i] = *(const short8*)&at[wm * 64 + i * 16 + l15][kk * 32 + quad * 8];
            #pragma unroll
            for (int j = 0; j < 4; ++j)
                bg[j] = *(const short8*)&bt[wb * 64 + j * 16 + l15][kk * 32 + quad * 8];
            #pragma unroll
            for (int i = 0; i < 4; ++i)
                #pragma unroll
                for (int j = 0; j < 4; ++j)
                    acc[i][j] = __builtin_amdgcn_mfma_f32_16x16x32_bf16(af[i], bg[j], acc[i][j], 0, 0, 0);
        }
    }

    // group epilogue: frag i == 16-row group (wm*4+i). Cross-quad shuffle, no atomics.
    #pragma unroll
    for (int i = 0; i < 4; ++i)
        #pragma unroll
        for (int j = 0; j < 4; ++j) {
            uint32_t k = 0;
            #pragma unroll
            for (int r = 0; r < 4; ++r) {
                uint32_t kk = f32_order(acc[i][j][r]);   // already cos * |ctx|
                k = kk > k ? kk : k;
            }
            uint32_t o1 = __shfl_xor(k, 16, 64); k = o1 > k ? o1 : k;
            uint32_t o2 = __shfl_xor(k, 32, 64); k = o2 > k ? o2 : k;
            if (quad == 0) s_gbest[wm * 4 + i][wb * 64 + j * 16 + l15] = k;
        }
    __syncthreads();

    if (!coarse) {
        const int G0 = blockIdx.y * 8;
        for (int e = t; e < 8 * BB; e += 256) {
            const int col = e >> 3, g = e & 7;
            tmax[(size_t)(b0 + col) * 4096 + G0 + g] = s_gbest[g][col];
        }
    } else {
        if (t < BB) {
            uint32_t k = s_gbest[0][t];
            #pragma unroll
            for (int g = 1; g < 8; ++g) k = s_gbest[g][t] > k ? s_gbest[g][t] : k;
            tmax[(size_t)(b0 + t) * 512 + blockIdx.y] = k;
        }
    }
}

// ---- legacy kernel 1 (fallback when workspace too small for bf16 copies) ----
__global__ __launch_bounds__(256) void score_phase1(const void* __restrict__ ctxv,
                                                    const void* __restrict__ memv,
                                                    const uint32_t* __restrict__ flag,
                                                    uint32_t* __restrict__ tmax,
                                                    int coarse) {
    __shared__ __align__(16) uint16_t at[BM][LDSPAD];
    __shared__ __align__(16) uint16_t bt[BB][LDSPAD];
    __shared__ float s_nsq[BM];
    __shared__ uint32_t s_gbest[8][BB];

    const int t    = threadIdx.x;
    const int b0   = blockIdx.x * BB;
    const int m0   = blockIdx.y * BM;
    const int lane = t & 63;
    const int w    = t >> 6;
    const int wm   = w >> 1;
    const int wb   = w & 1;
    const int quad = lane >> 4;
    const int l15  = lane & 15;
    const int srow = t >> 2;
    const int scol = (t & 3) * 8;

    floatx4 acc[4][4];
    #pragma unroll
    for (int i = 0; i < 4; ++i)
        #pragma unroll
        for (int j = 0; j < 4; ++j)
            acc[i][j] = (floatx4){0.f, 0.f, 0.f, 0.f};

    float nsq0 = 0.f, nsq1 = 0.f;
    const bool isbf = (*flag != 0u);

    for (int k0 = 0; k0 < D_DIM; k0 += BK) {
        __syncthreads();
        if (isbf) {
            const uint16_t* mp = (const uint16_t*)memv;
            const uint16_t* cp = (const uint16_t*)ctxv;
            uint4 va0 = *(const uint4*)(mp + (size_t)(m0 + srow) * D_DIM + k0 + scol);
            uint4 va1 = *(const uint4*)(mp + (size_t)(m0 + srow + 64) * D_DIM + k0 + scol);
            uint4 vb0 = *(const uint4*)(cp + (size_t)(b0 + srow) * D_DIM + k0 + scol);
            uint4 vb1 = *(const uint4*)(cp + (size_t)(b0 + srow + 64) * D_DIM + k0 + scol);
            *(uint4*)&at[srow][scol] = va0;
            *(uint4*)&at[srow + 64][scol] = va1;
            *(uint4*)&bt[srow][scol] = vb0;
            *(uint4*)&bt[srow + 64][scol] = vb1;
            uint32_t wa0[4] = {va0.x, va0.y, va0.z, va0.w};
            uint32_t wa1[4] = {va1.x, va1.y, va1.z, va1.w};
            #pragma unroll
            for (int i = 0; i < 4; ++i) {
                float a = __uint_as_float(wa0[i] << 16);
                float b = __uint_as_float(wa0[i] & 0xFFFF0000u);
                nsq0 = fmaf(a, a, nsq0); nsq0 = fmaf(b, b, nsq0);
                float c = __uint_as_float(wa1[i] << 16);
                float d = __uint_as_float(wa1[i] & 0xFFFF0000u);
                nsq1 = fmaf(c, c, nsq1); nsq1 = fmaf(d, d, nsq1);
            }
        } else {
            const float* mp = (const float*)memv;
            const float* cp = (const float*)ctxv;
            const float4* pa0 = (const float4*)(mp + (size_t)(m0 + srow) * D_DIM + k0 + scol);
            const float4* pa1 = (const float4*)(mp + (size_t)(m0 + srow + 64) * D_DIM + k0 + scol);
            const float4* pb0 = (const float4*)(cp + (size_t)(b0 + srow) * D_DIM + k0 + scol);
            const float4* pb1 = (const float4*)(cp + (size_t)(b0 + srow + 64) * D_DIM + k0 + scol);
            float4 a0 = pa0[0], a1 = pa0[1], a2 = pa1[0], a3 = pa1[1];
            float4 c0 = pb0[0], c1 = pb0[1], c2 = pb1[0], c3 = pb1[1];
            uint4 va0 = {pack_bf16_rtn(a0.x, a0.y), pack_bf16_rtn(a0.z, a0.w),
                         pack_bf16_rtn(a1.x, a1.y), pack_bf16_rtn(a1.z, a1.w)};
            uint4 va1 = {pack_bf16_rtn(a2.x, a2.y), pack_bf16_rtn(a2.z, a2.w),
                         pack_bf16_rtn(a3.x, a3.y), pack_bf16_rtn(a3.z, a3.w)};
            uint4 vb0 = {pack_bf16_rtn(c0.x, c0.y), pack_bf16_rtn(c0.z, c0.w),
                         pack_bf16_rtn(c1.x, c1.y), pack_bf16_rtn(c1.z, c1.w)};
            uint4 vb1 = {pack_bf16_rtn(c2.x, c2.y), pack_bf16_rtn(c2.z, c2.w),
                         pack_bf16_rtn(c3.x, c3.y), pack_bf16_rtn(c3.z, c3.w)};
            *(uint4*)&at[srow][scol] = va0;
            *(uint4*)&at[srow + 64][scol] = va1;
            *(uint4*)&bt[srow][scol] = vb0;
            *(uint4*)&bt[srow + 64][scol] = vb1;
            nsq0 = fmaf(a0.x, a0.x, nsq0); nsq0 = fmaf(a0.y, a0.y, nsq0);
            nsq0 = fmaf(a0.z, a0.z, nsq0); nsq0 = fmaf(a0.w, a0.w, nsq0);
            nsq0 = fmaf(a1.x, a1.x, nsq0); nsq0 = fmaf(a1.y, a1.y, nsq0);
            nsq0 = fmaf(a1.z, a1.z, nsq0); nsq0 = fmaf(a1.w, a1.w, nsq0);
            nsq1 = fmaf(a2.x, a2.x, nsq1); nsq1 = fmaf(a2.y, a2.y, nsq1);
            nsq1 = fmaf(a2.z, a2.z, nsq1); nsq1 = fmaf(a2.w, a2.w, nsq1);
            nsq1 = fmaf(a3.x, a3.x, nsq1); nsq1 = fmaf(a3.y, a3.y, nsq1);
            nsq1 = fmaf(a3.z, a3.z, nsq1); nsq1 = fmaf(a3.w, a3.w, nsq1);
        }
        __syncthreads();

        short8 af[4], bg[4];
        #pragma unroll
        for (int i = 0; i < 4; ++i)
            af[i] = *(const short8*)&at[wm * 64 + i * 16 + l15][quad * 8];
        #pragma unroll
        for (int j = 0; j < 4; ++j)
            bg[j] = *(const short8*)&bt[wb * 64 + j * 16 + l15][quad * 8];

        #pragma unroll
        for (int i = 0; i < 4; ++i)
            #pragma unroll
            for (int j = 0; j < 4; ++j)
                acc[i][j] = __builtin_amdgcn_mfma_f32_16x16x32_bf16(af[i], bg[j], acc[i][j], 0, 0, 0);
    }

    nsq0 += __shfl_xor(nsq0, 1, 64); nsq0 += __shfl_xor(nsq0, 2, 64);
    nsq1 += __shfl_xor(nsq1, 1, 64); nsq1 += __shfl_xor(nsq1, 2, 64);
    __syncthreads();
    if ((t & 3) == 0) { s_nsq[srow] = nsq0; s_nsq[srow + 64] = nsq1; }
    __syncthreads();

    float invn[4][4];
    #pragma unroll
    for (int i = 0; i < 4; ++i)
        #pragma unroll
        for (int r = 0; r < 4; ++r)
            invn[i][r] = rsqrtf(fmaxf(s_nsq[wm * 64 + i * 16 + quad * 4 + r], 1e-12f));

    #pragma unroll
    for (int i = 0; i < 4; ++i)
        #pragma unroll
        for (int j = 0; j < 4; ++j) {
            uint32_t k = 0;
            #pragma unroll
            for (int r = 0; r < 4; ++r) {
                uint32_t kk = f32_order(acc[i][j][r] * invn[i][r]);
                k = kk > k ? kk : k;
            }
            uint32_t o1 = __shfl_xor(k, 16, 64); k = o1 > k ? o1 : k;
            uint32_t o2 = __shfl_xor(k, 32, 64); k = o2 > k ? o2 : k;
            if (quad == 0) s_gbest[wm * 4 + i][wb * 64 + j * 16 + l15] = k;
        }
    __syncthreads();

    if (!coarse) {
        const int G0 = blockIdx.y * 8;
        for (int e = t; e < 8 * BB; e += 256) {
            const int col = e >> 3, g = e & 7;
            tmax[(size_t)(b0 + col) * 4096 + G0 + g] = s_gbest[g][col];
        }
    } else {
        if (t < BB) {
            uint32_t k = s_gbest[0][t];
            #pragma unroll
            for (int g = 1; g < 8; ++g) k = s_gbest[g][t] > k ? s_gbest[g][t] : k;
            tmax[(size_t)(b0 + t) * 512 + blockIdx.y] = k;
        }
    }
}

// ---------------- kernel 2: exact fp64 rescore of candidate groups + gather ----------------
__global__ __launch_bounds__(256) void phase2(const void* __restrict__ ctxv,
                                              const void* __restrict__ memv,
                                              const uint32_t* __restrict__ flag,
                                              const uint32_t* __restrict__ tmax,
                                              void* __restrict__ outv,
                                              int ngrp, int gshift) {
    __shared__ float s_ctx[D_DIM];
    __shared__ int s_list[LISTCAP];
    __shared__ int s_cnt;
    __shared__ uint32_t s_red[4];
    __shared__ float s_cn[4];
    __shared__ double s_d[4], s_n[4];
    __shared__ int s_m[4];
    __shared__ int s_bestm;

    const int b = blockIdx.x;
    const int t = threadIdx.x;
    const int lane = t & 63;
    const int w = t >> 6;
    const bool isbf = (*flag != 0u);
    const int gmask = (1 << gshift) - 1;

    if (t == 0) s_cnt = 0;
    if (isbf) {
        if (t < 64) {
            uint4 v = *((const uint4*)((const uint16_t*)ctxv + (size_t)b * D_DIM) + t);
            uint32_t ww[4] = {v.x, v.y, v.z, v.w};
            #pragma unroll
            for (int i = 0; i < 4; ++i) {
                s_ctx[t * 8 + 2 * i]     = __uint_as_float(ww[i] << 16);
                s_ctx[t * 8 + 2 * i + 1] = __uint_as_float(ww[i] & 0xFFFF0000u);
            }
        }
    } else {
        if (t < 128)
            ((float4*)s_ctx)[t] = ((const float4*)((const float*)ctxv + (size_t)b * D_DIM))[t];
    }
    __syncthreads();

    // ctx norm (scale-invariant rescan margin)
    float cs = s_ctx[t] * s_ctx[t] + s_ctx[t + 256] * s_ctx[t + 256];
    #pragma unroll
    for (int o = 32; o; o >>= 1) cs += __shfl_xor(cs, o, 64);
    if (lane == 0) s_cn[w] = cs;

    // scan this b's group keys (coalesced), find block max.
    // NOTE: no kv[] array (runtime-indexed arrays go to scratch); re-read L2-hot keys.
    const uint32_t* tk = tmax + (size_t)b * ngrp;
    const int nk = ngrp >> 8;          // 16 (fine) or 2 (coarse)
    uint32_t km = 0;
    for (int i = 0; i < nk; ++i) {
        uint32_t v = tk[t + (i << 8)];
        km = v > km ? v : km;
    }
    #pragma unroll
    for (int o = 32; o; o >>= 1) { uint32_t ot = __shfl_xor(km, o, 64); km = ot > km ? ot : km; }
    if (lane == 0) s_red[w] = km;
    __syncthreads();
    uint32_t kbest = s_red[0];
    #pragma unroll
    for (int i = 1; i < 4; ++i) kbest = s_red[i] > kbest ? s_red[i] : kbest;
    const float cnorm = sqrtf(s_cn[0] + s_cn[1] + s_cn[2] + s_cn[3]);
    const uint32_t keyT = f32_order(f32_unorder(kbest) - DELTA_COS * cnorm);

    for (int i = 0; i < nk; ++i) {
        uint32_t v = tk[t + (i << 8)];
        if (v >= keyT) {
            int idx = atomicAdd(&s_cnt, 1);
            if (idx < LISTCAP) s_list[idx] = t + (i << 8);
        }
    }
    __syncthreads();
    int cnt = s_cnt; if (cnt > LISTCAP) cnt = LISTCAP;
    const int total = cnt << gshift;

    // best = (dot, nsq, m); compare via signed-square cross-multiplication
    double bd = -1.0e300, bn = 1.0;
    double bp = bd * 1.0e300;   // -inf
    int bm = 0x7FFFFFFF;
    const float* cb = s_ctx + lane * 8;

    for (int base = w * 2; base < total; base += 8) {
        const bool has1 = (base + 1 < total);
        const int ia = base, ib = has1 ? base + 1 : base;
        const int ma = (s_list[ia >> gshift] << gshift) + (ia & gmask);
        const int mb = (s_list[ib >> gshift] << gshift) + (ib & gmask);
        double d0 = 0.0, n0 = 0.0, d1 = 0.0, n1 = 0.0;
        if (isbf) {
            uint4 va = *((const uint4*)((const uint16_t*)memv + (size_t)ma * D_DIM) + lane);
            uint4 vb = *((const uint4*)((const uint16_t*)memv + (size_t)mb * D_DIM) + lane);
            uint32_t wa[4] = {va.x, va.y, va.z, va.w};
            uint32_t wbv[4] = {vb.x, vb.y, vb.z, vb.w};
            #pragma unroll
            for (int i = 0; i < 4; ++i) {
                float a0 = __uint_as_float(wa[i] << 16);
                float a1 = __uint_as_float(wa[i] & 0xFFFF0000u);
                d0 += (double)a0 * (double)cb[2 * i];
                d0 += (double)a1 * (double)cb[2 * i + 1];
                n0 += (double)a0 * (double)a0 + (double)a1 * (double)a1;
                float b0v = __uint_as_float(wbv[i] << 16);
                float b1v = __uint_as_float(wbv[i] & 0xFFFF0000u);
                d1 += (double)b0v * (double)cb[2 * i];
                d1 += (double)b1v * (double)cb[2 * i + 1];
                n1 += (double)b0v * (double)b0v + (double)b1v * (double)b1v;
            }
        } else {
            const float4* pa = (const float4*)((const float*)memv + (size_t)ma * D_DIM) + lane * 2;
            const float4* pb = (const float4*)((const float*)memv + (size_t)mb * D_DIM) + lane * 2;
            float4 a0 = pa[0], a1 = pa[1], b0v = pb[0], b1v = pb[1];
            float xa[8] = {a0.x, a0.y, a0.z, a0.w, a1.x, a1.y, a1.z, a1.w};
            float xb[8] = {b0v.x, b0v.y, b0v.z, b0v.w, b1v.x, b1v.y, b1v.z, b1v.w};
            #pragma unroll
            for (int i = 0; i < 8; ++i) {
                d0 += (double)xa[i] * (double)cb[i];
                n0 += (double)xa[i] * (double)xa[i];
                d1 += (double)xb[i] * (double)cb[i];
                n1 += (double)xb[i] * (double)xb[i];
            }
        }
        #pragma unroll
        for (int o = 32; o; o >>= 1) {
            d0 += __shfl_xor(d0, o, 64);
            n0 += __shfl_xor(n0, o, 64);
            d1 += __shfl_xor(d1, o, 64);
            n1 += __shfl_xor(n1, o, 64);
        }
        double p0 = d0 * fabs(d0);
        double lhs = p0 * bn, rhs = bp * n0;
        if (lhs > rhs || (lhs == rhs && ma < bm)) { bd = d0; bn = n0; bp = p0; bm = ma; }
        if (has1) {
            double p1 = d1 * fabs(d1);
            double lhs1 = p1 * bn, rhs1 = bp * n1;
            if (lhs1 > rhs1 || (lhs1 == rhs1 && mb < bm)) { bd = d1; bn = n1; bp = p1; bm = mb; }
        }
    }
    if (lane == 0) { s_d[w] = bd; s_n[w] = bn; s_m[w] = bm; }
    __syncthreads();
    if (t == 0) {
        double cd = s_d[0], cn2 = s_n[0], cp = cd * fabs(cd);
        int cm = s_m[0];
        #pragma unroll
        for (int i = 1; i < 4; ++i) {
            double pd = s_d[i], pn = s_n[i], pp = pd * fabs(pd);
            double lhs = pp * cn2, rhs = cp * pn;
            if (lhs > rhs || (lhs == rhs && s_m[i] < cm)) { cd = pd; cn2 = pn; cp = pp; cm = s_m[i]; }
        }
        s_bestm = cm;
    }
    __syncthreads();
    const int mbest = s_bestm;
    if (isbf) {
        if (t < 64)
            ((uint4*)((uint16_t*)outv + (size_t)b * D_DIM))[t] =
                ((const uint4*)((const uint16_t*)memv + (size_t)mbest * D_DIM))[t];
    } else {
        if (t < 128)
            ((float4*)((float*)outv + (size_t)b * D_DIM))[t] =
                ((const float4*)((const float*)memv + (size_t)mbest * D_DIM))[t];
    }
}

extern "C" void kernel_launch(void* const* d_in, const int* in_sizes, int n_in,
                              void* d_out, int out_size, void* d_ws, size_t ws_size,
                              hipStream_t stream) {
    const void* ctx = d_in[0];
    const void* mem = d_in[1];
    if (in_sizes[0] > in_sizes[1]) { ctx = d_in[1]; mem = d_in[0]; }  // ctx is smaller

    const size_t fineBytes   = (size_t)B_CTX * 4096 * 4;   // 8 MB
    const size_t coarseBytes = (size_t)B_CTX * 512 * 4;    // 1 MB
    const size_t ctxBytes    = (size_t)B_CTX * D_DIM * 2;  // 0.5 MB
    const size_t memBytes    = (size_t)M_MEM * D_DIM * 2;  // 64 MB
    const size_t fastBytes   = fineBytes + 256 + ctxBytes + memBytes;  // ~72.5 MB
    dim3 grid(B_CTX / BB, M_MEM / BM);

    if (ws_size >= fastBytes) {
        // fast path: one-pass convert+normalize, then pure-bf16 global_load_lds GEMM
        uint32_t* tmax  = (uint32_t*)d_ws;
        uint32_t* flag  = (uint32_t*)((char*)d_ws + fineBytes);
        uint16_t* ctx_b = (uint16_t*)((char*)d_ws + fineBytes + 256);
        uint16_t* mem_s = (uint16_t*)((char*)d_ws + fineBytes + 256 + ctxBytes);
        detect_init<<<1, 64, 0, stream>>>((const uint32_t*)mem, flag);
        convert_scale<<<CVT_BLOCKS, 256, 0, stream>>>(ctx, mem, flag, mem_s, ctx_b);
        score_mfma<<<grid, 256, 0, stream>>>(mem_s, ctx_b, tmax, 0);
        phase2<<<B_CTX, 256, 0, stream>>>(ctx, mem, flag, tmax, d_out, 4096, 4);
    } else if (ws_size >= fineBytes + 256) {
        uint32_t* tmax = (uint32_t*)d_ws;
        uint32_t* flag = (uint32_t*)((char*)d_ws + fineBytes);
        detect_init<<<1, 64, 0, stream>>>((const uint32_t*)mem, flag);
        score_phase1<<<grid, 256, 0, stream>>>(ctx, mem, flag, tmax, 0);
        phase2<<<B_CTX, 256, 0, stream>>>(ctx, mem, flag, tmax, d_out, 4096, 4);
    } else {
        uint32_t* tmax = (uint32_t*)d_ws;
        uint32_t* flag = (uint32_t*)((char*)d_ws + coarseBytes);
        detect_init<<<1, 64, 0, stream>>>((const uint32_t*)mem, flag);
        score_phase1<<<grid, 256, 0, stream>>>(ctx, mem, flag, tmax, 1);
        phase2<<<B_CTX, 256, 0, stream>>>(ctx, mem, flag, tmax, d_out, 512, 7);
    }
}

// Round 3
// 288.476 us; speedup vs baseline: 1.0175x; 1.0175x over previous
//
#include <hip/hip_runtime.h>
#include <hip/hip_bf16.h>
#include <stdint.h>

#define D_DIM 512
#define B_CTX 512
#define M_MEM 65536
#define BM 128
#define BB 128
#define BK 32
#define GBK 64               // K-step of the fast bf16 GEMM (m97 structure)
#define LDSPAD 40            // 80 B row pitch for legacy fallback kernel
#define DELTA_COS 2.5e-3f    // ~35 sigma of bf16 cosine noise, scale-invariant
#define LISTCAP 2048
#define CVT_MEM_BLOCKS (M_MEM / 32)            // 2048: 4 waves x 8 rows each
#define CVT_BLOCKS (CVT_MEM_BLOCKS + B_CTX / 32)

typedef __attribute__((ext_vector_type(8))) short short8;   // 8 bf16 (4 VGPR)
typedef __attribute__((ext_vector_type(4))) float floatx4;  // MFMA accumulator

__device__ __forceinline__ uint32_t f32_order(float s) {    // monotone f32->u32
    uint32_t u = __float_as_uint(s);
    return (u & 0x80000000u) ? ~u : (u | 0x80000000u);
}
__device__ __forceinline__ float f32_unorder(uint32_t v) {
    uint32_t u = (v & 0x80000000u) ? (v & 0x7FFFFFFFu) : ~v;
    return __uint_as_float(u);
}
__device__ __forceinline__ uint32_t pack_bf16_rtn(float a, float b) {
    uint32_t ua = __float_as_uint(a) + 0x8000u;
    uint32_t ub = __float_as_uint(b) + 0x8000u;
    return (ua >> 16) | (ub & 0xFFFF0000u);
}

// async global->LDS, 16B per lane. LDS dest is WAVE-UNIFORM base; HW adds lane*16.
typedef const __attribute__((address_space(1))) void gv_t;
typedef __attribute__((address_space(3))) void lv_t;
__device__ __forceinline__ void gload_lds16(const uint16_t* g, uint16_t* l) {
    __builtin_amdgcn_global_load_lds((gv_t*)g, (lv_t*)l, 16, 0, 0);
}

// ---------------- kernel 0: dtype probe ----------------
__global__ void detect_init(const uint32_t* __restrict__ mem_raw,
                            uint32_t* __restrict__ flag) {
    __shared__ int cnt;
    if (threadIdx.x == 0) cnt = 0;
    __syncthreads();
    int s = 0;
    #pragma unroll
    for (int i = 0; i < 8; ++i) {
        uint32_t u = mem_raw[threadIdx.x * 8 + i];
        uint32_t e = (u >> 7) & 0xFFu;   // exponent of LOW bf16 half
        s += (e >= 96u && e <= 144u) ? 1 : 0;
    }
    atomicAdd(&cnt, s);
    __syncthreads();
    if (threadIdx.x == 0) *flag = (cnt > 256) ? 1u : 0u;   // 1 == bf16 inputs
}

// ---- kernel A: one-pass convert. mem -> bf16(mem * 1/|mem|), ctx -> bf16(ctx) ----
// One wave per 8 rows; lane holds 8 contiguous elements (32B fp32 in, 16B bf16 out).
__global__ __launch_bounds__(256) void convert_scale(const void* __restrict__ ctxv,
                                                     const void* __restrict__ memv,
                                                     const uint32_t* __restrict__ flag,
                                                     uint16_t* __restrict__ mem_s,
                                                     uint16_t* __restrict__ ctx_b) {
    const bool isbf = (*flag != 0u);
    const int lane = threadIdx.x & 63;
    const int w = threadIdx.x >> 6;
    if (blockIdx.x < CVT_MEM_BLOCKS) {
        const int gw = blockIdx.x * 4 + w;           // 0..8191
        #pragma unroll
        for (int i = 0; i < 8; ++i) {
            const int r = gw * 8 + i;                // 0..65535
            float x[8];
            if (isbf) {
                uint4 v = *((const uint4*)((const uint16_t*)memv + (size_t)r * D_DIM) + lane);
                uint32_t ww[4] = {v.x, v.y, v.z, v.w};
                #pragma unroll
                for (int j = 0; j < 4; ++j) {
                    x[2 * j]     = __uint_as_float(ww[j] << 16);
                    x[2 * j + 1] = __uint_as_float(ww[j] & 0xFFFF0000u);
                }
            } else {
                const float4* p = (const float4*)((const float*)memv + (size_t)r * D_DIM) + lane * 2;
                float4 a = p[0], bq = p[1];
                x[0] = a.x; x[1] = a.y; x[2] = a.z; x[3] = a.w;
                x[4] = bq.x; x[5] = bq.y; x[6] = bq.z; x[7] = bq.w;
            }
            float nsq = 0.f;
            #pragma unroll
            for (int j = 0; j < 8; ++j) nsq = fmaf(x[j], x[j], nsq);
            #pragma unroll
            for (int o = 32; o; o >>= 1) nsq += __shfl_xor(nsq, o, 64);
            const float invn = rsqrtf(fmaxf(nsq, 1e-12f));
            uint4 ov;
            ov.x = pack_bf16_rtn(x[0] * invn, x[1] * invn);
            ov.y = pack_bf16_rtn(x[2] * invn, x[3] * invn);
            ov.z = pack_bf16_rtn(x[4] * invn, x[5] * invn);
            ov.w = pack_bf16_rtn(x[6] * invn, x[7] * invn);
            *((uint4*)(mem_s + (size_t)r * D_DIM) + lane) = ov;
        }
    } else {
        const int gw = (blockIdx.x - CVT_MEM_BLOCKS) * 4 + w;   // 0..63
        #pragma unroll
        for (int i = 0; i < 8; ++i) {
            const int r = gw * 8 + i;                // 0..511
            uint4 ov;
            if (isbf) {
                ov = *((const uint4*)((const uint16_t*)ctxv + (size_t)r * D_DIM) + lane);
            } else {
                const float4* p = (const float4*)((const float*)ctxv + (size_t)r * D_DIM) + lane * 2;
                float4 a = p[0], bq = p[1];
                ov.x = pack_bf16_rtn(a.x, a.y);
                ov.y = pack_bf16_rtn(a.z, a.w);
                ov.z = pack_bf16_rtn(bq.x, bq.y);
                ov.w = pack_bf16_rtn(bq.z, bq.w);
            }
            *((uint4*)(ctx_b + (size_t)r * D_DIM) + lane) = ov;
        }
    }
}

// ---- kernel B: pure-bf16 MFMA GEMM (m97 structure: linear LDS dest via
// global_load_lds + T2 chunk-XOR swizzle applied on the GLOBAL source and the
// ds_read side; rule #21 both-sides-or-neither). Keys pre-normalized. ----
__global__ __launch_bounds__(256) void score_mfma(const uint16_t* __restrict__ A,   // mem_s [M][512]
                                                  const uint16_t* __restrict__ Bc,  // ctx_b [B][512]
                                                  uint32_t* __restrict__ tmax,
                                                  int coarse) {
    __shared__ __align__(16) uint16_t at[BM][GBK];   // 16 KB, LINEAR dest
    __shared__ __align__(16) uint16_t bt[BB][GBK];   // 16 KB
    __shared__ uint32_t s_gbest[8][BB];

    const int t    = threadIdx.x;
    const int b0   = blockIdx.x * BB;
    const int m0   = blockIdx.y * BM;
    const int lane = t & 63;
    const int w    = t >> 6;
    const int wm   = w >> 1;
    const int wb   = w & 1;
    const int quad = lane >> 4;
    const int l15  = lane & 15;
    const int srow = t >> 3;          // 0..31 (+32 per issue)
    // T2 swizzle: 16B chunk within the 128B row is XORed with (row&7).
    // Staging reads global chunk (chunk ^ row&7) into linear LDS chunk `chunk`;
    // same permutation applied on the read side -> involution, data correct,
    // and lanes 0..7 of a 16-lane group span all 32 banks (2-way residual = free).
    const int scol_sw = (((t & 7) ^ ((t >> 3) & 7)) << 3);   // element col, pre-swizzled
    const int xr = l15 & 7;                                  // read-side row XOR

    floatx4 acc[4][4];
    #pragma unroll
    for (int i = 0; i < 4; ++i)
        #pragma unroll
        for (int j = 0; j < 4; ++j)
            acc[i][j] = (floatx4){0.f, 0.f, 0.f, 0.f};

    for (int k0 = 0; k0 < D_DIM; k0 += GBK) {
        __syncthreads();               // previous tile's ds_reads done
        #pragma unroll
        for (int q = 0; q < 4; ++q) {
            const int r = srow + q * 32;
            // wave-uniform LDS base (chunks q*256 + w*64); HW scatters lane i at +i*16B.
            gload_lds16(A  + (size_t)(m0 + r) * D_DIM + k0 + scol_sw,
                        &at[0][0] + (size_t)(q * 256 + (w << 6)) * 8);
            gload_lds16(Bc + (size_t)(b0 + r) * D_DIM + k0 + scol_sw,
                        &bt[0][0] + (size_t)(q * 256 + (w << 6)) * 8);
        }
        __syncthreads();               // compiler drains vmcnt(0) here
        #pragma unroll
        for (int kk = 0; kk < 2; ++kk) {
            short8 af[4], bg[4];
            const int rc = ((kk * 4 + quad) ^ xr) << 3;   // swizzled element col
            #pragma unroll
            for (int i = 0; i < 4; ++i)
                af[i] = *(const short8*)&at[wm * 64 + i * 16 + l15][rc];
            #pragma unroll
            for (int j = 0; j < 4; ++j)
                bg[j] = *(const short8*)&bt[wb * 64 + j * 16 + l15][rc];
            #pragma unroll
            for (int i = 0; i < 4; ++i)
                #pragma unroll
                for (int j = 0; j < 4; ++j)
                    acc[i][j] = __builtin_amdgcn_mfma_f32_16x16x32_bf16(af[i], bg[j], acc[i][j], 0, 0, 0);
        }
    }

    // group epilogue: frag i == 16-row group (wm*4+i). Cross-quad shuffle, no atomics.
    #pragma unroll
    for (int i = 0; i < 4; ++i)
        #pragma unroll
        for (int j = 0; j < 4; ++j) {
            uint32_t k = 0;
            #pragma unroll
            for (int r = 0; r < 4; ++r) {
                uint32_t kk = f32_order(acc[i][j][r]);   // already cos * |ctx|
                k = kk > k ? kk : k;
            }
            uint32_t o1 = __shfl_xor(k, 16, 64); k = o1 > k ? o1 : k;
            uint32_t o2 = __shfl_xor(k, 32, 64); k = o2 > k ? o2 : k;
            if (quad == 0) s_gbest[wm * 4 + i][wb * 64 + j * 16 + l15] = k;
        }
    __syncthreads();

    if (!coarse) {
        const int G0 = blockIdx.y * 8;
        for (int e = t; e < 8 * BB; e += 256) {
            const int col = e >> 3, g = e & 7;
            tmax[(size_t)(b0 + col) * 4096 + G0 + g] = s_gbest[g][col];
        }
    } else {
        if (t < BB) {
            uint32_t k = s_gbest[0][t];
            #pragma unroll
            for (int g = 1; g < 8; ++g) k = s_gbest[g][t] > k ? s_gbest[g][t] : k;
            tmax[(size_t)(b0 + t) * 512 + blockIdx.y] = k;
        }
    }
}

// ---- legacy kernel 1 (fallback when workspace too small for bf16 copies) ----
__global__ __launch_bounds__(256) void score_phase1(const void* __restrict__ ctxv,
                                                    const void* __restrict__ memv,
                                                    const uint32_t* __restrict__ flag,
                                                    uint32_t* __restrict__ tmax,
                                                    int coarse) {
    __shared__ __align__(16) uint16_t at[BM][LDSPAD];
    __shared__ __align__(16) uint16_t bt[BB][LDSPAD];
    __shared__ float s_nsq[BM];
    __shared__ uint32_t s_gbest[8][BB];

    const int t    = threadIdx.x;
    const int b0   = blockIdx.x * BB;
    const int m0   = blockIdx.y * BM;
    const int lane = t & 63;
    const int w    = t >> 6;
    const int wm   = w >> 1;
    const int wb   = w & 1;
    const int quad = lane >> 4;
    const int l15  = lane & 15;
    const int srow = t >> 2;
    const int scol = (t & 3) * 8;

    floatx4 acc[4][4];
    #pragma unroll
    for (int i = 0; i < 4; ++i)
        #pragma unroll
        for (int j = 0; j < 4; ++j)
            acc[i][j] = (floatx4){0.f, 0.f, 0.f, 0.f};

    float nsq0 = 0.f, nsq1 = 0.f;
    const bool isbf = (*flag != 0u);

    for (int k0 = 0; k0 < D_DIM; k0 += BK) {
        __syncthreads();
        if (isbf) {
            const uint16_t* mp = (const uint16_t*)memv;
            const uint16_t* cp = (const uint16_t*)ctxv;
            uint4 va0 = *(const uint4*)(mp + (size_t)(m0 + srow) * D_DIM + k0 + scol);
            uint4 va1 = *(const uint4*)(mp + (size_t)(m0 + srow + 64) * D_DIM + k0 + scol);
            uint4 vb0 = *(const uint4*)(cp + (size_t)(b0 + srow) * D_DIM + k0 + scol);
            uint4 vb1 = *(const uint4*)(cp + (size_t)(b0 + srow + 64) * D_DIM + k0 + scol);
            *(uint4*)&at[srow][scol] = va0;
            *(uint4*)&at[srow + 64][scol] = va1;
            *(uint4*)&bt[srow][scol] = vb0;
            *(uint4*)&bt[srow + 64][scol] = vb1;
            uint32_t wa0[4] = {va0.x, va0.y, va0.z, va0.w};
            uint32_t wa1[4] = {va1.x, va1.y, va1.z, va1.w};
            #pragma unroll
            for (int i = 0; i < 4; ++i) {
                float a = __uint_as_float(wa0[i] << 16);
                float b = __uint_as_float(wa0[i] & 0xFFFF0000u);
                nsq0 = fmaf(a, a, nsq0); nsq0 = fmaf(b, b, nsq0);
                float c = __uint_as_float(wa1[i] << 16);
                float d = __uint_as_float(wa1[i] & 0xFFFF0000u);
                nsq1 = fmaf(c, c, nsq1); nsq1 = fmaf(d, d, nsq1);
            }
        } else {
            const float* mp = (const float*)memv;
            const float* cp = (const float*)ctxv;
            const float4* pa0 = (const float4*)(mp + (size_t)(m0 + srow) * D_DIM + k0 + scol);
            const float4* pa1 = (const float4*)(mp + (size_t)(m0 + srow + 64) * D_DIM + k0 + scol);
            const float4* pb0 = (const float4*)(cp + (size_t)(b0 + srow) * D_DIM + k0 + scol);
            const float4* pb1 = (const float4*)(cp + (size_t)(b0 + srow + 64) * D_DIM + k0 + scol);
            float4 a0 = pa0[0], a1 = pa0[1], a2 = pa1[0], a3 = pa1[1];
            float4 c0 = pb0[0], c1 = pb0[1], c2 = pb1[0], c3 = pb1[1];
            uint4 va0 = {pack_bf16_rtn(a0.x, a0.y), pack_bf16_rtn(a0.z, a0.w),
                         pack_bf16_rtn(a1.x, a1.y), pack_bf16_rtn(a1.z, a1.w)};
            uint4 va1 = {pack_bf16_rtn(a2.x, a2.y), pack_bf16_rtn(a2.z, a2.w),
                         pack_bf16_rtn(a3.x, a3.y), pack_bf16_rtn(a3.z, a3.w)};
            uint4 vb0 = {pack_bf16_rtn(c0.x, c0.y), pack_bf16_rtn(c0.z, c0.w),
                         pack_bf16_rtn(c1.x, c1.y), pack_bf16_rtn(c1.z, c1.w)};
            uint4 vb1 = {pack_bf16_rtn(c2.x, c2.y), pack_bf16_rtn(c2.z, c2.w),
                         pack_bf16_rtn(c3.x, c3.y), pack_bf16_rtn(c3.z, c3.w)};
            *(uint4*)&at[srow][scol] = va0;
            *(uint4*)&at[srow + 64][scol] = va1;
            *(uint4*)&bt[srow][scol] = vb0;
            *(uint4*)&bt[srow + 64][scol] = vb1;
            nsq0 = fmaf(a0.x, a0.x, nsq0); nsq0 = fmaf(a0.y, a0.y, nsq0);
            nsq0 = fmaf(a0.z, a0.z, nsq0); nsq0 = fmaf(a0.w, a0.w, nsq0);
            nsq0 = fmaf(a1.x, a1.x, nsq0); nsq0 = fmaf(a1.y, a1.y, nsq0);
            nsq0 = fmaf(a1.z, a1.z, nsq0); nsq0 = fmaf(a1.w, a1.w, nsq0);
            nsq1 = fmaf(a2.x, a2.x, nsq1); nsq1 = fmaf(a2.y, a2.y, nsq1);
            nsq1 = fmaf(a2.z, a2.z, nsq1); nsq1 = fmaf(a2.w, a2.w, nsq1);
            nsq1 = fmaf(a3.x, a3.x, nsq1); nsq1 = fmaf(a3.y, a3.y, nsq1);
            nsq1 = fmaf(a3.z, a3.z, nsq1); nsq1 = fmaf(a3.w, a3.w, nsq1);
        }
        __syncthreads();

        short8 af[4], bg[4];
        #pragma unroll
        for (int i = 0; i < 4; ++i)
            af[i] = *(const short8*)&at[wm * 64 + i * 16 + l15][quad * 8];
        #pragma unroll
        for (int j = 0; j < 4; ++j)
            bg[j] = *(const short8*)&bt[wb * 64 + j * 16 + l15][quad * 8];

        #pragma unroll
        for (int i = 0; i < 4; ++i)
            #pragma unroll
            for (int j = 0; j < 4; ++j)
                acc[i][j] = __builtin_amdgcn_mfma_f32_16x16x32_bf16(af[i], bg[j], acc[i][j], 0, 0, 0);
    }

    nsq0 += __shfl_xor(nsq0, 1, 64); nsq0 += __shfl_xor(nsq0, 2, 64);
    nsq1 += __shfl_xor(nsq1, 1, 64); nsq1 += __shfl_xor(nsq1, 2, 64);
    __syncthreads();
    if ((t & 3) == 0) { s_nsq[srow] = nsq0; s_nsq[srow + 64] = nsq1; }
    __syncthreads();

    float invn[4][4];
    #pragma unroll
    for (int i = 0; i < 4; ++i)
        #pragma unroll
        for (int r = 0; r < 4; ++r)
            invn[i][r] = rsqrtf(fmaxf(s_nsq[wm * 64 + i * 16 + quad * 4 + r], 1e-12f));

    #pragma unroll
    for (int i = 0; i < 4; ++i)
        #pragma unroll
        for (int j = 0; j < 4; ++j) {
            uint32_t k = 0;
            #pragma unroll
            for (int r = 0; r < 4; ++r) {
                uint32_t kk = f32_order(acc[i][j][r] * invn[i][r]);
                k = kk > k ? kk : k;
            }
            uint32_t o1 = __shfl_xor(k, 16, 64); k = o1 > k ? o1 : k;
            uint32_t o2 = __shfl_xor(k, 32, 64); k = o2 > k ? o2 : k;
            if (quad == 0) s_gbest[wm * 4 + i][wb * 64 + j * 16 + l15] = k;
        }
    __syncthreads();

    if (!coarse) {
        const int G0 = blockIdx.y * 8;
        for (int e = t; e < 8 * BB; e += 256) {
            const int col = e >> 3, g = e & 7;
            tmax[(size_t)(b0 + col) * 4096 + G0 + g] = s_gbest[g][col];
        }
    } else {
        if (t < BB) {
            uint32_t k = s_gbest[0][t];
            #pragma unroll
            for (int g = 1; g < 8; ++g) k = s_gbest[g][t] > k ? s_gbest[g][t] : k;
            tmax[(size_t)(b0 + t) * 512 + blockIdx.y] = k;
        }
    }
}

// ---------------- kernel 2: exact fp64 rescore of candidate groups + gather ----------------
__global__ __launch_bounds__(256) void phase2(const void* __restrict__ ctxv,
                                              const void* __restrict__ memv,
                                              const uint32_t* __restrict__ flag,
                                              const uint32_t* __restrict__ tmax,
                                              void* __restrict__ outv,
                                              int ngrp, int gshift) {
    __shared__ float s_ctx[D_DIM];
    __shared__ int s_list[LISTCAP];
    __shared__ int s_cnt;
    __shared__ uint32_t s_red[4];
    __shared__ float s_cn[4];
    __shared__ double s_d[4], s_n[4];
    __shared__ int s_m[4];
    __shared__ int s_bestm;

    const int b = blockIdx.x;
    const int t = threadIdx.x;
    const int lane = t & 63;
    const int w = t >> 6;
    const bool isbf = (*flag != 0u);
    const int gmask = (1 << gshift) - 1;

    if (t == 0) s_cnt = 0;
    if (isbf) {
        if (t < 64) {
            uint4 v = *((const uint4*)((const uint16_t*)ctxv + (size_t)b * D_DIM) + t);
            uint32_t ww[4] = {v.x, v.y, v.z, v.w};
            #pragma unroll
            for (int i = 0; i < 4; ++i) {
                s_ctx[t * 8 + 2 * i]     = __uint_as_float(ww[i] << 16);
                s_ctx[t * 8 + 2 * i + 1] = __uint_as_float(ww[i] & 0xFFFF0000u);
            }
        }
    } else {
        if (t < 128)
            ((float4*)s_ctx)[t] = ((const float4*)((const float*)ctxv + (size_t)b * D_DIM))[t];
    }
    __syncthreads();

    // ctx norm (scale-invariant rescan margin)
    float cs = s_ctx[t] * s_ctx[t] + s_ctx[t + 256] * s_ctx[t + 256];
    #pragma unroll
    for (int o = 32; o; o >>= 1) cs += __shfl_xor(cs, o, 64);
    if (lane == 0) s_cn[w] = cs;

    // scan this b's group keys (coalesced), find block max.
    // NOTE: no kv[] array (runtime-indexed arrays go to scratch); re-read L2-hot keys.
    const uint32_t* tk = tmax + (size_t)b * ngrp;
    const int nk = ngrp >> 8;          // 16 (fine) or 2 (coarse)
    uint32_t km = 0;
    for (int i = 0; i < nk; ++i) {
        uint32_t v = tk[t + (i << 8)];
        km = v > km ? v : km;
    }
    #pragma unroll
    for (int o = 32; o; o >>= 1) { uint32_t ot = __shfl_xor(km, o, 64); km = ot > km ? ot : km; }
    if (lane == 0) s_red[w] = km;
    __syncthreads();
    uint32_t kbest = s_red[0];
    #pragma unroll
    for (int i = 1; i < 4; ++i) kbest = s_red[i] > kbest ? s_red[i] : kbest;
    const float cnorm = sqrtf(s_cn[0] + s_cn[1] + s_cn[2] + s_cn[3]);
    const uint32_t keyT = f32_order(f32_unorder(kbest) - DELTA_COS * cnorm);

    for (int i = 0; i < nk; ++i) {
        uint32_t v = tk[t + (i << 8)];
        if (v >= keyT) {
            int idx = atomicAdd(&s_cnt, 1);
            if (idx < LISTCAP) s_list[idx] = t + (i << 8);
        }
    }
    __syncthreads();
    int cnt = s_cnt; if (cnt > LISTCAP) cnt = LISTCAP;
    const int total = cnt << gshift;

    // best = (dot, nsq, m); compare via signed-square cross-multiplication
    double bd = -1.0e300, bn = 1.0;
    double bp = bd * 1.0e300;   // -inf
    int bm = 0x7FFFFFFF;
    const float* cb = s_ctx + lane * 8;

    for (int base = w * 2; base < total; base += 8) {
        const bool has1 = (base + 1 < total);
        const int ia = base, ib = has1 ? base + 1 : base;
        const int ma = (s_list[ia >> gshift] << gshift) + (ia & gmask);
        const int mb = (s_list[ib >> gshift] << gshift) + (ib & gmask);
        double d0 = 0.0, n0 = 0.0, d1 = 0.0, n1 = 0.0;
        if (isbf) {
            uint4 va = *((const uint4*)((const uint16_t*)memv + (size_t)ma * D_DIM) + lane);
            uint4 vb = *((const uint4*)((const uint16_t*)memv + (size_t)mb * D_DIM) + lane);
            uint32_t wa[4] = {va.x, va.y, va.z, va.w};
            uint32_t wbv[4] = {vb.x, vb.y, vb.z, vb.w};
            #pragma unroll
            for (int i = 0; i < 4; ++i) {
                float a0 = __uint_as_float(wa[i] << 16);
                float a1 = __uint_as_float(wa[i] & 0xFFFF0000u);
                d0 += (double)a0 * (double)cb[2 * i];
                d0 += (double)a1 * (double)cb[2 * i + 1];
                n0 += (double)a0 * (double)a0 + (double)a1 * (double)a1;
                float b0v = __uint_as_float(wbv[i] << 16);
                float b1v = __uint_as_float(wbv[i] & 0xFFFF0000u);
                d1 += (double)b0v * (double)cb[2 * i];
                d1 += (double)b1v * (double)cb[2 * i + 1];
                n1 += (double)b0v * (double)b0v + (double)b1v * (double)b1v;
            }
        } else {
            const float4* pa = (const float4*)((const float*)memv + (size_t)ma * D_DIM) + lane * 2;
            const float4* pb = (const float4*)((const float*)memv + (size_t)mb * D_DIM) + lane * 2;
            float4 a0 = pa[0], a1 = pa[1], b0v = pb[0], b1v = pb[1];
            float xa[8] = {a0.x, a0.y, a0.z, a0.w, a1.x, a1.y, a1.z, a1.w};
            float xb[8] = {b0v.x, b0v.y, b0v.z, b0v.w, b1v.x, b1v.y, b1v.z, b1v.w};
            #pragma unroll
            for (int i = 0; i < 8; ++i) {
                d0 += (double)xa[i] * (double)cb[i];
                n0 += (double)xa[i] * (double)xa[i];
                d1 += (double)xb[i] * (double)cb[i];
                n1 += (double)xb[i] * (double)xb[i];
            }
        }
        #pragma unroll
        for (int o = 32; o; o >>= 1) {
            d0 += __shfl_xor(d0, o, 64);
            n0 += __shfl_xor(n0, o, 64);
            d1 += __shfl_xor(d1, o, 64);
            n1 += __shfl_xor(n1, o, 64);
        }
        double p0 = d0 * fabs(d0);
        double lhs = p0 * bn, rhs = bp * n0;
        if (lhs > rhs || (lhs == rhs && ma < bm)) { bd = d0; bn = n0; bp = p0; bm = ma; }
        if (has1) {
            double p1 = d1 * fabs(d1);
            double lhs1 = p1 * bn, rhs1 = bp * n1;
            if (lhs1 > rhs1 || (lhs1 == rhs1 && mb < bm)) { bd = d1; bn = n1; bp = p1; bm = mb; }
        }
    }
    if (lane == 0) { s_d[w] = bd; s_n[w] = bn; s_m[w] = bm; }
    __syncthreads();
    if (t == 0) {
        double cd = s_d[0], cn2 = s_n[0], cp = cd * fabs(cd);
        int cm = s_m[0];
        #pragma unroll
        for (int i = 1; i < 4; ++i) {
            double pd = s_d[i], pn = s_n[i], pp = pd * fabs(pd);
            double lhs = pp * cn2, rhs = cp * pn;
            if (lhs > rhs || (lhs == rhs && s_m[i] < cm)) { cd = pd; cn2 = pn; cp = pp; cm = s_m[i]; }
        }
        s_bestm = cm;
    }
    __syncthreads();
    const int mbest = s_bestm;
    if (isbf) {
        if (t < 64)
            ((uint4*)((uint16_t*)outv + (size_t)b * D_DIM))[t] =
                ((const uint4*)((const uint16_t*)memv + (size_t)mbest * D_DIM))[t];
    } else {
        if (t < 128)
            ((float4*)((float*)outv + (size_t)b * D_DIM))[t] =
                ((const float4*)((const float*)memv + (size_t)mbest * D_DIM))[t];
    }
}

extern "C" void kernel_launch(void* const* d_in, const int* in_sizes, int n_in,
                              void* d_out, int out_size, void* d_ws, size_t ws_size,
                              hipStream_t stream) {
    const void* ctx = d_in[0];
    const void* mem = d_in[1];
    if (in_sizes[0] > in_sizes[1]) { ctx = d_in[1]; mem = d_in[0]; }  // ctx is smaller

    const size_t fineBytes   = (size_t)B_CTX * 4096 * 4;   // 8 MB
    const size_t coarseBytes = (size_t)B_CTX * 512 * 4;    // 1 MB
    const size_t ctxBytes    = (size_t)B_CTX * D_DIM * 2;  // 0.5 MB
    const size_t memBytes    = (size_t)M_MEM * D_DIM * 2;  // 64 MB
    const size_t fastBytes   = fineBytes + 256 + ctxBytes + memBytes;  // ~72.5 MB
    dim3 grid(B_CTX / BB, M_MEM / BM);

    if (ws_size >= fastBytes) {
        // fast path: one-pass convert+normalize, then pure-bf16 global_load_lds GEMM
        uint32_t* tmax  = (uint32_t*)d_ws;
        uint32_t* flag  = (uint32_t*)((char*)d_ws + fineBytes);
        uint16_t* ctx_b = (uint16_t*)((char*)d_ws + fineBytes + 256);
        uint16_t* mem_s = (uint16_t*)((char*)d_ws + fineBytes + 256 + ctxBytes);
        detect_init<<<1, 64, 0, stream>>>((const uint32_t*)mem, flag);
        convert_scale<<<CVT_BLOCKS, 256, 0, stream>>>(ctx, mem, flag, mem_s, ctx_b);
        score_mfma<<<grid, 256, 0, stream>>>(mem_s, ctx_b, tmax, 0);
        phase2<<<B_CTX, 256, 0, stream>>>(ctx, mem, flag, tmax, d_out, 4096, 4);
    } else if (ws_size >= fineBytes + 256) {
        uint32_t* tmax = (uint32_t*)d_ws;
        uint32_t* flag = (uint32_t*)((char*)d_ws + fineBytes);
        detect_init<<<1, 64, 0, stream>>>((const uint32_t*)mem, flag);
        score_phase1<<<grid, 256, 0, stream>>>(ctx, mem, flag, tmax, 0);
        phase2<<<B_CTX, 256, 0, stream>>>(ctx, mem, flag, tmax, d_out, 4096, 4);
    } else {
        uint32_t* tmax = (uint32_t*)d_ws;
        uint32_t* flag = (uint32_t*)((char*)d_ws + coarseBytes);
        detect_init<<<1, 64, 0, stream>>>((const uint32_t*)mem, flag);
        score_phase1<<<grid, 256, 0, stream>>>(ctx, mem, flag, tmax, 1);
        phase2<<<B_CTX, 256, 0, stream>>>(ctx, mem, flag, tmax, d_out, 512, 7);
    }
}

// Round 4
// 271.157 us; speedup vs baseline: 1.0825x; 1.0639x over previous
//
#include <hip/hip_runtime.h>
#include <hip/hip_bf16.h>
#include <stdint.h>

#define D_DIM 512
#define B_CTX 512
#define M_MEM 65536
#define BM 128
#define BB 128
#define BK 32
#define GBK 32               // K-step of the fast bf16 GEMM (prefetch-dbuf structure)
#define LDSPAD 40            // 80 B row pitch for legacy fallback kernel
#define DELTA_COS 2.5e-3f    // ~35 sigma of bf16 cosine noise, scale-invariant
#define LISTCAP 2048
#define CVT_MEM_BLOCKS (M_MEM / 32)            // 2048: 4 waves x 8 rows each
#define CVT_BLOCKS (CVT_MEM_BLOCKS + B_CTX / 32)

typedef __attribute__((ext_vector_type(8))) short short8;   // 8 bf16 (4 VGPR)
typedef __attribute__((ext_vector_type(4))) float floatx4;  // MFMA accumulator

__device__ __forceinline__ uint32_t f32_order(float s) {    // monotone f32->u32
    uint32_t u = __float_as_uint(s);
    return (u & 0x80000000u) ? ~u : (u | 0x80000000u);
}
__device__ __forceinline__ float f32_unorder(uint32_t v) {
    uint32_t u = (v & 0x80000000u) ? (v & 0x7FFFFFFFu) : ~v;
    return __uint_as_float(u);
}
__device__ __forceinline__ uint32_t pack_bf16_rtn(float a, float b) {
    uint32_t ua = __float_as_uint(a) + 0x8000u;
    uint32_t ub = __float_as_uint(b) + 0x8000u;
    return (ua >> 16) | (ub & 0xFFFF0000u);
}

// async global->LDS, 16B per lane. LDS dest is WAVE-UNIFORM base; HW adds lane*16.
typedef const __attribute__((address_space(1))) void gv_t;
typedef __attribute__((address_space(3))) void lv_t;
__device__ __forceinline__ void gload_lds16(const uint16_t* g, uint16_t* l) {
    __builtin_amdgcn_global_load_lds((gv_t*)g, (lv_t*)l, 16, 0, 0);
}

// ---------------- kernel 0: dtype probe ----------------
__global__ void detect_init(const uint32_t* __restrict__ mem_raw,
                            uint32_t* __restrict__ flag) {
    __shared__ int cnt;
    if (threadIdx.x == 0) cnt = 0;
    __syncthreads();
    int s = 0;
    #pragma unroll
    for (int i = 0; i < 8; ++i) {
        uint32_t u = mem_raw[threadIdx.x * 8 + i];
        uint32_t e = (u >> 7) & 0xFFu;   // exponent of LOW bf16 half
        s += (e >= 96u && e <= 144u) ? 1 : 0;
    }
    atomicAdd(&cnt, s);
    __syncthreads();
    if (threadIdx.x == 0) *flag = (cnt > 256) ? 1u : 0u;   // 1 == bf16 inputs
}

// ---- kernel A: one-pass convert. mem -> bf16(mem * 1/|mem|), ctx -> bf16(ctx) ----
__global__ __launch_bounds__(256) void convert_scale(const void* __restrict__ ctxv,
                                                     const void* __restrict__ memv,
                                                     const uint32_t* __restrict__ flag,
                                                     uint16_t* __restrict__ mem_s,
                                                     uint16_t* __restrict__ ctx_b) {
    const bool isbf = (*flag != 0u);
    const int lane = threadIdx.x & 63;
    const int w = threadIdx.x >> 6;
    if (blockIdx.x < CVT_MEM_BLOCKS) {
        const int gw = blockIdx.x * 4 + w;           // 0..8191
        #pragma unroll
        for (int i = 0; i < 8; ++i) {
            const int r = gw * 8 + i;                // 0..65535
            float x[8];
            if (isbf) {
                uint4 v = *((const uint4*)((const uint16_t*)memv + (size_t)r * D_DIM) + lane);
                uint32_t ww[4] = {v.x, v.y, v.z, v.w};
                #pragma unroll
                for (int j = 0; j < 4; ++j) {
                    x[2 * j]     = __uint_as_float(ww[j] << 16);
                    x[2 * j + 1] = __uint_as_float(ww[j] & 0xFFFF0000u);
                }
            } else {
                const float4* p = (const float4*)((const float*)memv + (size_t)r * D_DIM) + lane * 2;
                float4 a = p[0], bq = p[1];
                x[0] = a.x; x[1] = a.y; x[2] = a.z; x[3] = a.w;
                x[4] = bq.x; x[5] = bq.y; x[6] = bq.z; x[7] = bq.w;
            }
            float nsq = 0.f;
            #pragma unroll
            for (int j = 0; j < 8; ++j) nsq = fmaf(x[j], x[j], nsq);
            #pragma unroll
            for (int o = 32; o; o >>= 1) nsq += __shfl_xor(nsq, o, 64);
            const float invn = rsqrtf(fmaxf(nsq, 1e-12f));
            uint4 ov;
            ov.x = pack_bf16_rtn(x[0] * invn, x[1] * invn);
            ov.y = pack_bf16_rtn(x[2] * invn, x[3] * invn);
            ov.z = pack_bf16_rtn(x[4] * invn, x[5] * invn);
            ov.w = pack_bf16_rtn(x[6] * invn, x[7] * invn);
            *((uint4*)(mem_s + (size_t)r * D_DIM) + lane) = ov;
        }
    } else {
        const int gw = (blockIdx.x - CVT_MEM_BLOCKS) * 4 + w;   // 0..63
        #pragma unroll
        for (int i = 0; i < 8; ++i) {
            const int r = gw * 8 + i;                // 0..511
            uint4 ov;
            if (isbf) {
                ov = *((const uint4*)((const uint16_t*)ctxv + (size_t)r * D_DIM) + lane);
            } else {
                const float4* p = (const float4*)((const float*)ctxv + (size_t)r * D_DIM) + lane * 2;
                float4 a = p[0], bq = p[1];
                ov.x = pack_bf16_rtn(a.x, a.y);
                ov.y = pack_bf16_rtn(a.z, a.w);
                ov.z = pack_bf16_rtn(bq.x, bq.y);
                ov.w = pack_bf16_rtn(bq.z, bq.w);
            }
            *((uint4*)(ctx_b + (size_t)r * D_DIM) + lane) = ov;
        }
    }
}

// ---- kernel B: pure-bf16 MFMA GEMM, T3-minimum prefetch double-buffer:
// STAGE(next) issued BEFORE compute(cur); ONE barrier (vmcnt0 drain) per K-step.
// GBK=32 dbuf keeps LDS at 36KB -> 4 blocks/CU. T2 swizzle via pre-swizzled
// global source + swizzled ds_read (rule #21). XCD-chunked block remap so the
// 4 blocks sharing an A-tile land on the same XCD L2. Keys pre-normalized. ----
#define STAGE(buf, kofs)                                                          \
    do {                                                                          \
        gload_lds16(ga0 + (kofs), &at[buf][0][0] + (size_t)((w << 6)) * 8);       \
        gload_lds16(ga1 + (kofs), &at[buf][0][0] + (size_t)(256 + (w << 6)) * 8); \
        gload_lds16(gb0 + (kofs), &bt[buf][0][0] + (size_t)((w << 6)) * 8);       \
        gload_lds16(gb1 + (kofs), &bt[buf][0][0] + (size_t)(256 + (w << 6)) * 8); \
    } while (0)

__global__ __launch_bounds__(256, 4) void score_mfma(const uint16_t* __restrict__ A,   // mem_s [M][512]
                                                     const uint16_t* __restrict__ Bc,  // ctx_b [B][512]
                                                     uint32_t* __restrict__ tmax,
                                                     int coarse) {
    __shared__ __align__(16) uint16_t at[2][BM][GBK];   // 2 x 8KB, LINEAR dest
    __shared__ __align__(16) uint16_t bt[2][BB][GBK];   // 2 x 8KB
    __shared__ uint32_t s_gbest[8][BB];

    // XCD-chunked remap: HW round-robins flat id across 8 XCDs (h&7). Map so each
    // XCD owns a contiguous strip of m-panels covering all 4 b-panels -> the 4
    // blocks sharing an A-tile share one L2. Bijection: v = (h&7)*256 + (h>>3).
    const int h  = blockIdx.y * gridDim.x + blockIdx.x;   // 0..2047
    const int v  = (h & 7) * 256 + (h >> 3);
    const int bxp = v & 3;                                // b-panel 0..3
    const int byp = v >> 2;                               // m-panel 0..511

    const int t    = threadIdx.x;
    const int b0   = bxp * BB;
    const int m0   = byp * BM;
    const int lane = t & 63;
    const int w    = t >> 6;
    const int wm   = w >> 1;
    const int wb   = w & 1;
    const int quad = lane >> 4;
    const int l15  = lane & 15;
    const int srow = t >> 2;          // 0..63 (chunk row, +64 for second issue)
    // T2 swizzle for 64B row pitch: 16B chunk-in-row (0..3) XOR ((row>>1)&3).
    // Stage pulls global chunk (r, j^f(r)) into linear LDS chunk (r, j); read
    // applies the same XOR -> involution; 16-lane read groups spread over all
    // 8 bank-groups (2-way residual = free, m136).
    const int scol_sw = (((t & 3) ^ ((t >> 3) & 3)) << 3);   // staging: element col
    const int rc = ((quad ^ ((l15 >> 1) & 3)) << 3);         // read: element col

    const uint16_t* ga0 = A  + (size_t)(m0 + srow) * D_DIM + scol_sw;
    const uint16_t* ga1 = A  + (size_t)(m0 + srow + 64) * D_DIM + scol_sw;
    const uint16_t* gb0 = Bc + (size_t)(b0 + srow) * D_DIM + scol_sw;
    const uint16_t* gb1 = Bc + (size_t)(b0 + srow + 64) * D_DIM + scol_sw;

    floatx4 acc[4][4];
    #pragma unroll
    for (int i = 0; i < 4; ++i)
        #pragma unroll
        for (int j = 0; j < 4; ++j)
            acc[i][j] = (floatx4){0.f, 0.f, 0.f, 0.f};

    // prologue: stage tile 0, drain
    STAGE(0, 0);
    __syncthreads();

    int cur = 0;
    #pragma unroll
    for (int it = 0; it < (D_DIM / GBK) - 1; ++it) {
        STAGE(cur ^ 1, (it + 1) * GBK);   // issue next-tile loads FIRST (fly under compute)
        short8 af[4], bg[4];
        #pragma unroll
        for (int i = 0; i < 4; ++i)
            af[i] = *(const short8*)&at[cur][wm * 64 + i * 16 + l15][rc];
        #pragma unroll
        for (int j = 0; j < 4; ++j)
            bg[j] = *(const short8*)&bt[cur][wb * 64 + j * 16 + l15][rc];
        #pragma unroll
        for (int i = 0; i < 4; ++i)
            #pragma unroll
            for (int j = 0; j < 4; ++j)
                acc[i][j] = __builtin_amdgcn_mfma_f32_16x16x32_bf16(af[i], bg[j], acc[i][j], 0, 0, 0);
        __syncthreads();                  // single drain: vmcnt(0)+lgkmcnt(0)+barrier
        cur ^= 1;
    }
    {   // last tile: no prefetch
        short8 af[4], bg[4];
        #pragma unroll
        for (int i = 0; i < 4; ++i)
            af[i] = *(const short8*)&at[cur][wm * 64 + i * 16 + l15][rc];
        #pragma unroll
        for (int j = 0; j < 4; ++j)
            bg[j] = *(const short8*)&bt[cur][wb * 64 + j * 16 + l15][rc];
        #pragma unroll
        for (int i = 0; i < 4; ++i)
            #pragma unroll
            for (int j = 0; j < 4; ++j)
                acc[i][j] = __builtin_amdgcn_mfma_f32_16x16x32_bf16(af[i], bg[j], acc[i][j], 0, 0, 0);
    }

    // group epilogue: frag i == 16-row group (wm*4+i). Cross-quad shuffle, no atomics.
    #pragma unroll
    for (int i = 0; i < 4; ++i)
        #pragma unroll
        for (int j = 0; j < 4; ++j) {
            uint32_t k = 0;
            #pragma unroll
            for (int r = 0; r < 4; ++r) {
                uint32_t kk = f32_order(acc[i][j][r]);   // already cos * |ctx|
                k = kk > k ? kk : k;
            }
            uint32_t o1 = __shfl_xor(k, 16, 64); k = o1 > k ? o1 : k;
            uint32_t o2 = __shfl_xor(k, 32, 64); k = o2 > k ? o2 : k;
            if (quad == 0) s_gbest[wm * 4 + i][wb * 64 + j * 16 + l15] = k;
        }
    __syncthreads();

    if (!coarse) {
        const int G0 = byp * 8;
        for (int e = t; e < 8 * BB; e += 256) {
            const int col = e >> 3, g = e & 7;
            tmax[(size_t)(b0 + col) * 4096 + G0 + g] = s_gbest[g][col];
        }
    } else {
        if (t < BB) {
            uint32_t k = s_gbest[0][t];
            #pragma unroll
            for (int g = 1; g < 8; ++g) k = s_gbest[g][t] > k ? s_gbest[g][t] : k;
            tmax[(size_t)(b0 + t) * 512 + byp] = k;
        }
    }
}

// ---- legacy kernel 1 (fallback when workspace too small for bf16 copies) ----
__global__ __launch_bounds__(256) void score_phase1(const void* __restrict__ ctxv,
                                                    const void* __restrict__ memv,
                                                    const uint32_t* __restrict__ flag,
                                                    uint32_t* __restrict__ tmax,
                                                    int coarse) {
    __shared__ __align__(16) uint16_t at[BM][LDSPAD];
    __shared__ __align__(16) uint16_t bt[BB][LDSPAD];
    __shared__ float s_nsq[BM];
    __shared__ uint32_t s_gbest[8][BB];

    const int t    = threadIdx.x;
    const int b0   = blockIdx.x * BB;
    const int m0   = blockIdx.y * BM;
    const int lane = t & 63;
    const int w    = t >> 6;
    const int wm   = w >> 1;
    const int wb   = w & 1;
    const int quad = lane >> 4;
    const int l15  = lane & 15;
    const int srow = t >> 2;
    const int scol = (t & 3) * 8;

    floatx4 acc[4][4];
    #pragma unroll
    for (int i = 0; i < 4; ++i)
        #pragma unroll
        for (int j = 0; j < 4; ++j)
            acc[i][j] = (floatx4){0.f, 0.f, 0.f, 0.f};

    float nsq0 = 0.f, nsq1 = 0.f;
    const bool isbf = (*flag != 0u);

    for (int k0 = 0; k0 < D_DIM; k0 += BK) {
        __syncthreads();
        if (isbf) {
            const uint16_t* mp = (const uint16_t*)memv;
            const uint16_t* cp = (const uint16_t*)ctxv;
            uint4 va0 = *(const uint4*)(mp + (size_t)(m0 + srow) * D_DIM + k0 + scol);
            uint4 va1 = *(const uint4*)(mp + (size_t)(m0 + srow + 64) * D_DIM + k0 + scol);
            uint4 vb0 = *(const uint4*)(cp + (size_t)(b0 + srow) * D_DIM + k0 + scol);
            uint4 vb1 = *(const uint4*)(cp + (size_t)(b0 + srow + 64) * D_DIM + k0 + scol);
            *(uint4*)&at[srow][scol] = va0;
            *(uint4*)&at[srow + 64][scol] = va1;
            *(uint4*)&bt[srow][scol] = vb0;
            *(uint4*)&bt[srow + 64][scol] = vb1;
            uint32_t wa0[4] = {va0.x, va0.y, va0.z, va0.w};
            uint32_t wa1[4] = {va1.x, va1.y, va1.z, va1.w};
            #pragma unroll
            for (int i = 0; i < 4; ++i) {
                float a = __uint_as_float(wa0[i] << 16);
                float b = __uint_as_float(wa0[i] & 0xFFFF0000u);
                nsq0 = fmaf(a, a, nsq0); nsq0 = fmaf(b, b, nsq0);
                float c = __uint_as_float(wa1[i] << 16);
                float d = __uint_as_float(wa1[i] & 0xFFFF0000u);
                nsq1 = fmaf(c, c, nsq1); nsq1 = fmaf(d, d, nsq1);
            }
        } else {
            const float* mp = (const float*)memv;
            const float* cp = (const float*)ctxv;
            const float4* pa0 = (const float4*)(mp + (size_t)(m0 + srow) * D_DIM + k0 + scol);
            const float4* pa1 = (const float4*)(mp + (size_t)(m0 + srow + 64) * D_DIM + k0 + scol);
            const float4* pb0 = (const float4*)(cp + (size_t)(b0 + srow) * D_DIM + k0 + scol);
            const float4* pb1 = (const float4*)(cp + (size_t)(b0 + srow + 64) * D_DIM + k0 + scol);
            float4 a0 = pa0[0], a1 = pa0[1], a2 = pa1[0], a3 = pa1[1];
            float4 c0 = pb0[0], c1 = pb0[1], c2 = pb1[0], c3 = pb1[1];
            uint4 va0 = {pack_bf16_rtn(a0.x, a0.y), pack_bf16_rtn(a0.z, a0.w),
                         pack_bf16_rtn(a1.x, a1.y), pack_bf16_rtn(a1.z, a1.w)};
            uint4 va1 = {pack_bf16_rtn(a2.x, a2.y), pack_bf16_rtn(a2.z, a2.w),
                         pack_bf16_rtn(a3.x, a3.y), pack_bf16_rtn(a3.z, a3.w)};
            uint4 vb0 = {pack_bf16_rtn(c0.x, c0.y), pack_bf16_rtn(c0.z, c0.w),
                         pack_bf16_rtn(c1.x, c1.y), pack_bf16_rtn(c1.z, c1.w)};
            uint4 vb1 = {pack_bf16_rtn(c2.x, c2.y), pack_bf16_rtn(c2.z, c2.w),
                         pack_bf16_rtn(c3.x, c3.y), pack_bf16_rtn(c3.z, c3.w)};
            *(uint4*)&at[srow][scol] = va0;
            *(uint4*)&at[srow + 64][scol] = va1;
            *(uint4*)&bt[srow][scol] = vb0;
            *(uint4*)&bt[srow + 64][scol] = vb1;
            nsq0 = fmaf(a0.x, a0.x, nsq0); nsq0 = fmaf(a0.y, a0.y, nsq0);
            nsq0 = fmaf(a0.z, a0.z, nsq0); nsq0 = fmaf(a0.w, a0.w, nsq0);
            nsq0 = fmaf(a1.x, a1.x, nsq0); nsq0 = fmaf(a1.y, a1.y, nsq0);
            nsq0 = fmaf(a1.z, a1.z, nsq0); nsq0 = fmaf(a1.w, a1.w, nsq0);
            nsq1 = fmaf(a2.x, a2.x, nsq1); nsq1 = fmaf(a2.y, a2.y, nsq1);
            nsq1 = fmaf(a2.z, a2.z, nsq1); nsq1 = fmaf(a2.w, a2.w, nsq1);
            nsq1 = fmaf(a3.x, a3.x, nsq1); nsq1 = fmaf(a3.y, a3.y, nsq1);
            nsq1 = fmaf(a3.w, a3.w, nsq1); nsq1 = fmaf(a3.z, a3.z, nsq1);
        }
        __syncthreads();

        short8 af[4], bg[4];
        #pragma unroll
        for (int i = 0; i < 4; ++i)
            af[i] = *(const short8*)&at[wm * 64 + i * 16 + l15][quad * 8];
        #pragma unroll
        for (int j = 0; j < 4; ++j)
            bg[j] = *(const short8*)&bt[wb * 64 + j * 16 + l15][quad * 8];

        #pragma unroll
        for (int i = 0; i < 4; ++i)
            #pragma unroll
            for (int j = 0; j < 4; ++j)
                acc[i][j] = __builtin_amdgcn_mfma_f32_16x16x32_bf16(af[i], bg[j], acc[i][j], 0, 0, 0);
    }

    nsq0 += __shfl_xor(nsq0, 1, 64); nsq0 += __shfl_xor(nsq0, 2, 64);
    nsq1 += __shfl_xor(nsq1, 1, 64); nsq1 += __shfl_xor(nsq1, 2, 64);
    __syncthreads();
    if ((t & 3) == 0) { s_nsq[srow] = nsq0; s_nsq[srow + 64] = nsq1; }
    __syncthreads();

    float invn[4][4];
    #pragma unroll
    for (int i = 0; i < 4; ++i)
        #pragma unroll
        for (int r = 0; r < 4; ++r)
            invn[i][r] = rsqrtf(fmaxf(s_nsq[wm * 64 + i * 16 + quad * 4 + r], 1e-12f));

    #pragma unroll
    for (int i = 0; i < 4; ++i)
        #pragma unroll
        for (int j = 0; j < 4; ++j) {
            uint32_t k = 0;
            #pragma unroll
            for (int r = 0; r < 4; ++r) {
                uint32_t kk = f32_order(acc[i][j][r] * invn[i][r]);
                k = kk > k ? kk : k;
            }
            uint32_t o1 = __shfl_xor(k, 16, 64); k = o1 > k ? o1 : k;
            uint32_t o2 = __shfl_xor(k, 32, 64); k = o2 > k ? o2 : k;
            if (quad == 0) s_gbest[wm * 4 + i][wb * 64 + j * 16 + l15] = k;
        }
    __syncthreads();

    if (!coarse) {
        const int G0 = blockIdx.y * 8;
        for (int e = t; e < 8 * BB; e += 256) {
            const int col = e >> 3, g = e & 7;
            tmax[(size_t)(b0 + col) * 4096 + G0 + g] = s_gbest[g][col];
        }
    } else {
        if (t < BB) {
            uint32_t k = s_gbest[0][t];
            #pragma unroll
            for (int g = 1; g < 8; ++g) k = s_gbest[g][t] > k ? s_gbest[g][t] : k;
            tmax[(size_t)(b0 + t) * 512 + blockIdx.y] = k;
        }
    }
}

// ---------------- kernel 2: exact fp64 rescore of candidate groups + gather ----------------
__global__ __launch_bounds__(256) void phase2(const void* __restrict__ ctxv,
                                              const void* __restrict__ memv,
                                              const uint32_t* __restrict__ flag,
                                              const uint32_t* __restrict__ tmax,
                                              void* __restrict__ outv,
                                              int ngrp, int gshift) {
    __shared__ float s_ctx[D_DIM];
    __shared__ int s_list[LISTCAP];
    __shared__ int s_cnt;
    __shared__ uint32_t s_red[4];
    __shared__ float s_cn[4];
    __shared__ double s_d[4], s_n[4];
    __shared__ int s_m[4];
    __shared__ int s_bestm;

    const int b = blockIdx.x;
    const int t = threadIdx.x;
    const int lane = t & 63;
    const int w = t >> 6;
    const bool isbf = (*flag != 0u);
    const int gmask = (1 << gshift) - 1;

    if (t == 0) s_cnt = 0;
    if (isbf) {
        if (t < 64) {
            uint4 v = *((const uint4*)((const uint16_t*)ctxv + (size_t)b * D_DIM) + t);
            uint32_t ww[4] = {v.x, v.y, v.z, v.w};
            #pragma unroll
            for (int i = 0; i < 4; ++i) {
                s_ctx[t * 8 + 2 * i]     = __uint_as_float(ww[i] << 16);
                s_ctx[t * 8 + 2 * i + 1] = __uint_as_float(ww[i] & 0xFFFF0000u);
            }
        }
    } else {
        if (t < 128)
            ((float4*)s_ctx)[t] = ((const float4*)((const float*)ctxv + (size_t)b * D_DIM))[t];
    }
    __syncthreads();

    // ctx norm (scale-invariant rescan margin)
    float cs = s_ctx[t] * s_ctx[t] + s_ctx[t + 256] * s_ctx[t + 256];
    #pragma unroll
    for (int o = 32; o; o >>= 1) cs += __shfl_xor(cs, o, 64);
    if (lane == 0) s_cn[w] = cs;

    // scan this b's group keys (coalesced), find block max.
    const uint32_t* tk = tmax + (size_t)b * ngrp;
    const int nk = ngrp >> 8;          // 16 (fine) or 2 (coarse)
    uint32_t km = 0;
    for (int i = 0; i < nk; ++i) {
        uint32_t v = tk[t + (i << 8)];
        km = v > km ? v : km;
    }
    #pragma unroll
    for (int o = 32; o; o >>= 1) { uint32_t ot = __shfl_xor(km, o, 64); km = ot > km ? ot : km; }
    if (lane == 0) s_red[w] = km;
    __syncthreads();
    uint32_t kbest = s_red[0];
    #pragma unroll
    for (int i = 1; i < 4; ++i) kbest = s_red[i] > kbest ? s_red[i] : kbest;
    const float cnorm = sqrtf(s_cn[0] + s_cn[1] + s_cn[2] + s_cn[3]);
    const uint32_t keyT = f32_order(f32_unorder(kbest) - DELTA_COS * cnorm);

    for (int i = 0; i < nk; ++i) {
        uint32_t v = tk[t + (i << 8)];
        if (v >= keyT) {
            int idx = atomicAdd(&s_cnt, 1);
            if (idx < LISTCAP) s_list[idx] = t + (i << 8);
        }
    }
    __syncthreads();
    int cnt = s_cnt; if (cnt > LISTCAP) cnt = LISTCAP;
    const int total = cnt << gshift;

    // best = (dot, nsq, m); compare via signed-square cross-multiplication
    double bd = -1.0e300, bn = 1.0;
    double bp = bd * 1.0e300;   // -inf
    int bm = 0x7FFFFFFF;
    const float* cb = s_ctx + lane * 8;

    for (int base = w * 2; base < total; base += 8) {
        const bool has1 = (base + 1 < total);
        const int ia = base, ib = has1 ? base + 1 : base;
        const int ma = (s_list[ia >> gshift] << gshift) + (ia & gmask);
        const int mb = (s_list[ib >> gshift] << gshift) + (ib & gmask);
        double d0 = 0.0, n0 = 0.0, d1 = 0.0, n1 = 0.0;
        if (isbf) {
            uint4 va = *((const uint4*)((const uint16_t*)memv + (size_t)ma * D_DIM) + lane);
            uint4 vb = *((const uint4*)((const uint16_t*)memv + (size_t)mb * D_DIM) + lane);
            uint32_t wa[4] = {va.x, va.y, va.z, va.w};
            uint32_t wbv[4] = {vb.x, vb.y, vb.z, vb.w};
            #pragma unroll
            for (int i = 0; i < 4; ++i) {
                float a0 = __uint_as_float(wa[i] << 16);
                float a1 = __uint_as_float(wa[i] & 0xFFFF0000u);
                d0 += (double)a0 * (double)cb[2 * i];
                d0 += (double)a1 * (double)cb[2 * i + 1];
                n0 += (double)a0 * (double)a0 + (double)a1 * (double)a1;
                float b0v = __uint_as_float(wbv[i] << 16);
                float b1v = __uint_as_float(wbv[i] & 0xFFFF0000u);
                d1 += (double)b0v * (double)cb[2 * i];
                d1 += (double)b1v * (double)cb[2 * i + 1];
                n1 += (double)b0v * (double)b0v + (double)b1v * (double)b1v;
            }
        } else {
            const float4* pa = (const float4*)((const float*)memv + (size_t)ma * D_DIM) + lane * 2;
            const float4* pb = (const float4*)((const float*)memv + (size_t)mb * D_DIM) + lane * 2;
            float4 a0 = pa[0], a1 = pa[1], b0v = pb[0], b1v = pb[1];
            float xa[8] = {a0.x, a0.y, a0.z, a0.w, a1.x, a1.y, a1.z, a1.w};
            float xb[8] = {b0v.x, b0v.y, b0v.z, b0v.w, b1v.x, b1v.y, b1v.z, b1v.w};
            #pragma unroll
            for (int i = 0; i < 8; ++i) {
                d0 += (double)xa[i] * (double)cb[i];
                n0 += (double)xa[i] * (double)xa[i];
                d1 += (double)xb[i] * (double)cb[i];
                n1 += (double)xb[i] * (double)xb[i];
            }
        }
        #pragma unroll
        for (int o = 32; o; o >>= 1) {
            d0 += __shfl_xor(d0, o, 64);
            n0 += __shfl_xor(n0, o, 64);
            d1 += __shfl_xor(d1, o, 64);
            n1 += __shfl_xor(n1, o, 64);
        }
        double p0 = d0 * fabs(d0);
        double lhs = p0 * bn, rhs = bp * n0;
        if (lhs > rhs || (lhs == rhs && ma < bm)) { bd = d0; bn = n0; bp = p0; bm = ma; }
        if (has1) {
            double p1 = d1 * fabs(d1);
            double lhs1 = p1 * bn, rhs1 = bp * n1;
            if (lhs1 > rhs1 || (lhs1 == rhs1 && mb < bm)) { bd = d1; bn = n1; bp = p1; bm = mb; }
        }
    }
    if (lane == 0) { s_d[w] = bd; s_n[w] = bn; s_m[w] = bm; }
    __syncthreads();
    if (t == 0) {
        double cd = s_d[0], cn2 = s_n[0], cp = cd * fabs(cd);
        int cm = s_m[0];
        #pragma unroll
        for (int i = 1; i < 4; ++i) {
            double pd = s_d[i], pn = s_n[i], pp = pd * fabs(pd);
            double lhs = pp * cn2, rhs = cp * pn;
            if (lhs > rhs || (lhs == rhs && s_m[i] < cm)) { cd = pd; cn2 = pn; cp = pp; cm = s_m[i]; }
        }
        s_bestm = cm;
    }
    __syncthreads();
    const int mbest = s_bestm;
    if (isbf) {
        if (t < 64)
            ((uint4*)((uint16_t*)outv + (size_t)b * D_DIM))[t] =
                ((const uint4*)((const uint16_t*)memv + (size_t)mbest * D_DIM))[t];
    } else {
        if (t < 128)
            ((float4*)((float*)outv + (size_t)b * D_DIM))[t] =
                ((const float4*)((const float*)memv + (size_t)mbest * D_DIM))[t];
    }
}

extern "C" void kernel_launch(void* const* d_in, const int* in_sizes, int n_in,
                              void* d_out, int out_size, void* d_ws, size_t ws_size,
                              hipStream_t stream) {
    const void* ctx = d_in[0];
    const void* mem = d_in[1];
    if (in_sizes[0] > in_sizes[1]) { ctx = d_in[1]; mem = d_in[0]; }  // ctx is smaller

    const size_t fineBytes   = (size_t)B_CTX * 4096 * 4;   // 8 MB
    const size_t coarseBytes = (size_t)B_CTX * 512 * 4;    // 1 MB
    const size_t ctxBytes    = (size_t)B_CTX * D_DIM * 2;  // 0.5 MB
    const size_t memBytes    = (size_t)M_MEM * D_DIM * 2;  // 64 MB
    const size_t fastBytes   = fineBytes + 256 + ctxBytes + memBytes;  // ~72.5 MB
    dim3 grid(B_CTX / BB, M_MEM / BM);

    if (ws_size >= fastBytes) {
        // fast path: one-pass convert+normalize, then pure-bf16 prefetch-dbuf GEMM
        uint32_t* tmax  = (uint32_t*)d_ws;
        uint32_t* flag  = (uint32_t*)((char*)d_ws + fineBytes);
        uint16_t* ctx_b = (uint16_t*)((char*)d_ws + fineBytes + 256);
        uint16_t* mem_s = (uint16_t*)((char*)d_ws + fineBytes + 256 + ctxBytes);
        detect_init<<<1, 64, 0, stream>>>((const uint32_t*)mem, flag);
        convert_scale<<<CVT_BLOCKS, 256, 0, stream>>>(ctx, mem, flag, mem_s, ctx_b);
        score_mfma<<<grid, 256, 0, stream>>>(mem_s, ctx_b, tmax, 0);
        phase2<<<B_CTX, 256, 0, stream>>>(ctx, mem, flag, tmax, d_out, 4096, 4);
    } else if (ws_size >= fineBytes + 256) {
        uint32_t* tmax = (uint32_t*)d_ws;
        uint32_t* flag = (uint32_t*)((char*)d_ws + fineBytes);
        detect_init<<<1, 64, 0, stream>>>((const uint32_t*)mem, flag);
        score_phase1<<<grid, 256, 0, stream>>>(ctx, mem, flag, tmax, 0);
        phase2<<<B_CTX, 256, 0, stream>>>(ctx, mem, flag, tmax, d_out, 4096, 4);
    } else {
        uint32_t* tmax = (uint32_t*)d_ws;
        uint32_t* flag = (uint32_t*)((char*)d_ws + coarseBytes);
        detect_init<<<1, 64, 0, stream>>>((const uint32_t*)mem, flag);
        score_phase1<<<grid, 256, 0, stream>>>(ctx, mem, flag, tmax, 1);
        phase2<<<B_CTX, 256, 0, stream>>>(ctx, mem, flag, tmax, d_out, 512, 7);
    }
}